// Round 2
// baseline (903.094 us; speedup 1.0000x reference)
//
#include <hip/hip_runtime.h>
#include <math.h>

constexpr int NN = 40000;
constexpr int NE = 640000;
constexpr int KD = 129;     // contraction dim (time + 128 space)
constexpr int SD = 132;     // state row stride (16B-aligned)

// ---- transposed-weight buffer offsets (in floats) ----
constexpr int OFF_IN   = 0;
constexpr int OFF_QKV0 = OFF_IN   + KD*128;
constexpr int OFF_QKV1 = OFF_QKV0 + KD*384;
constexpr int OFF_OUT0 = OFF_QKV1 + KD*384;
constexpr int OFF_OUT1 = OFF_OUT0 + KD*128;
constexpr int OFF_OUTP = OFF_OUT1 + KD*128;
constexpr int WT_TOTAL = OFF_OUTP + KD*128;   // 165120 floats

struct QkvPtrs {
  float* sp0; float* tp0;
  float* sp1; float* tp1;
  float* sp2; float* tp2;
};

// =================== small utility kernels ===================

__global__ void zero_i32(int* p, int n) {
  int i = blockIdx.x * 256 + threadIdx.x;
  if (i < n) p[i] = 0;
}

// transpose all weights to k-major once per call
__global__ void prep_wt(const float* __restrict__ in_w, const float* __restrict__ q_w,
                        const float* __restrict__ k_w, const float* __restrict__ v_w,
                        const float* __restrict__ out_w, const float* __restrict__ outp_w,
                        float* __restrict__ WT) {
  int t = blockIdx.x * 256 + threadIdx.x;
  if (t >= KD * 1280) return;
  int k = t / 1280, c = t % 1280;
  float v; int dst;
  if (c < 128) {
    v = in_w[(size_t)c * KD + k];
    dst = OFF_IN + k * 128 + c;
  } else if (c < 896) {
    int l = (c - 128) / 384, cc = (c - 128) % 384;
    int arr = cc >> 7, r = cc & 127;
    const float* w = arr == 0 ? q_w : (arr == 1 ? k_w : v_w);
    v = w[((size_t)l * 128 + r) * KD + k];
    dst = (l == 0 ? OFF_QKV0 : OFF_QKV1) + k * 384 + cc;
  } else if (c < 1152) {
    int l = (c - 896) / 128, r = (c - 896) % 128;
    v = out_w[((size_t)l * 128 + r) * KD + k];
    dst = (l == 0 ? OFF_OUT0 : OFF_OUT1) + k * 128 + r;
  } else {
    int r = c - 1152;
    v = outp_w[(size_t)r * KD + k];
    dst = OFF_OUTP + k * 128 + r;
  }
  WT[dst] = v;
}

__global__ void prep_bias(const float* __restrict__ q_b, const float* __restrict__ k_b,
                          const float* __restrict__ v_b, float* __restrict__ bq) {
  int t = blockIdx.x * 256 + threadIdx.x;
  if (t >= 768) return;
  int l = t / 384, c = t % 384;
  int arr = c >> 7, r = c & 127;
  const float* b = arr == 0 ? q_b : (arr == 1 ? k_b : v_b);
  bq[t] = b[l * 128 + r];
}

// =================== CSR build ===================

__global__ void count_kernel(const int* __restrict__ dst, int* __restrict__ counts, int E) {
  int e = blockIdx.x * 256 + threadIdx.x;
  if (e < E) atomicAdd(&counts[dst[e]], 1);
}

__global__ void __launch_bounds__(1024) scan_kernel(const int* __restrict__ counts,
                                                    int* __restrict__ ro, int n) {
  __shared__ int wsum[16];
  __shared__ int carry;
  int tid = threadIdx.x, wid = tid >> 6, lane = tid & 63;
  if (tid == 0) { carry = 0; ro[0] = 0; }
  __syncthreads();
  for (int base = 0; base < n; base += 1024) {
    int idx = base + tid;
    int v = (idx < n) ? counts[idx] : 0;
    int s = v;
    #pragma unroll
    for (int off = 1; off < 64; off <<= 1) {
      int t = __shfl_up(s, off);
      if (lane >= off) s += t;
    }
    if (lane == 63) wsum[wid] = s;
    __syncthreads();
    if (wid == 0) {
      int ws = (lane < 16) ? wsum[lane] : 0;
      #pragma unroll
      for (int off = 1; off < 16; off <<= 1) {
        int t = __shfl_up(ws, off);
        if (lane >= off) ws += t;
      }
      if (lane < 16) wsum[lane] = ws;
    }
    __syncthreads();
    int woff = (wid > 0) ? wsum[wid - 1] : 0;
    if (idx < n) ro[idx + 1] = s + woff + carry;
    int total = wsum[15];
    __syncthreads();
    if (tid == 0) carry += total;
    __syncthreads();
  }
}

__global__ void scatter_kernel(const int* __restrict__ src, const int* __restrict__ dst,
                               const int* __restrict__ ro, int* __restrict__ cursor,
                               int* __restrict__ s_csr, int* __restrict__ d_csr,
                               int* __restrict__ e_csr, int E) {
  int e = blockIdx.x * 256 + threadIdx.x;
  if (e >= E) return;
  int d = dst[e];
  int pos = ro[d] + atomicAdd(&cursor[d], 1);
  s_csr[pos] = src[e];
  d_csr[pos] = d;
  e_csr[pos] = e;
}

// =================== expmap0 ===================
// block = 256 = 4 nodes x 64 lanes
__global__ void expmap_kernel(const float* __restrict__ x, float* __restrict__ h) {
  int nl = threadIdx.x >> 6, lane = threadIdx.x & 63;
  int n = blockIdx.x * 4 + nl;
  if (n >= NN) return;
  const float* xr = x + (size_t)n * 128;
  float v0 = xr[lane], v1 = xr[lane + 64];
  float ss = v0 * v0 + v1 * v1;
  #pragma unroll
  for (int off = 1; off < 64; off <<= 1) ss += __shfl_xor(ss, off);
  float nn = sqrtf(fmaxf(ss, 1e-12f));
  float s = sinhf(nn) / nn;
  float* hr = h + (size_t)n * SD;
  if (lane == 0) hr[0] = coshf(nn);
  hr[1 + lane] = s * v0;
  hr[1 + lane + 64] = s * v1;
}

// =================== fused node GEMM ===================
// 32 nodes x 128 cols per block; 256 threads; thread = (ln 0..15, lc 0..15)
// each thread: 2 nodes (2*ln, 2*ln+1) x 8 cols (lc*8 .. lc*8+7)
struct SMem {
  union {
    struct { float At[KD][32]; float Wc[32][144]; } a;  // 34944 B
    float Y[32][132];                                   // 16896 B
  } u;
  float sc[32];
};

// EPI: 0 = LN+ReLU+lift (in-proj), 1 = per-head lift (qkv),
//      2 = lift+midpoint+LN+lift (out-proj), 3 = lift+logmap0 (final)
template<int EPI>
__global__ __launch_bounds__(256) void node_gemm(
    const float* A, const float* __restrict__ WT, int outc,
    const float* __restrict__ bias, float* out0, QkvPtrs qo,
    const float* __restrict__ res, const float* __restrict__ g,
    const float* __restrict__ bv) {
  __shared__ SMem sm;
  const int tid = threadIdx.x;
  const int lc = tid & 15, ln = tid >> 4;
  const int ln2 = ln << 1;
  const int node0 = blockIdx.x * 32;
  const int cb = blockIdx.y;
  const int colOff = cb << 7;

  // A-tile, transposed: At[k][node]; float4 global loads, conflict-free stores
  for (int idx = tid; idx < 32 * 33; idx += 256) {
    int nl = idx & 31, c = idx >> 5;
    const float* ar = A + (size_t)(node0 + nl) * SD;
    if (c < 32) {
      float4 v = *(const float4*)(ar + (c << 2));
      int k = c << 2;
      sm.u.a.At[k][nl] = v.x;
      sm.u.a.At[k + 1][nl] = v.y;
      sm.u.a.At[k + 2][nl] = v.z;
      sm.u.a.At[k + 3][nl] = v.w;
    } else {
      sm.u.a.At[128][nl] = ar[128];
    }
  }
  float acc0[8], acc1[8];
  #pragma unroll
  for (int j = 0; j < 8; j++) { acc0[j] = 0.f; acc1[j] = 0.f; }
  const int wb = (lc >> 2) * 36 + ((lc & 3) << 3);

  for (int kc = 0; kc < 128; kc += 32) {
    __syncthreads();
    #pragma unroll
    for (int i = tid; i < 1024; i += 256) {   // stage W chunk [32][128] -> padded groups
      int kk = i >> 5, c4 = (i & 31) << 2;
      float4 w = *(const float4*)(WT + (size_t)(kc + kk) * outc + colOff + c4);
      *(float4*)&sm.u.a.Wc[kk][(c4 >> 5) * 36 + (c4 & 31)] = w;
    }
    __syncthreads();
    #pragma unroll 8
    for (int kk = 0; kk < 32; ++kk) {
      const float2 a = *(const float2*)&sm.u.a.At[kc + kk][ln2];
      const float* wr = &sm.u.a.Wc[kk][wb];
      float w[8];
      *(float4*)&w[0] = *(const float4*)wr;
      *(float4*)&w[4] = *(const float4*)(wr + 4);
      #pragma unroll
      for (int j = 0; j < 8; j++) {
        acc0[j] = fmaf(a.x, w[j], acc0[j]);
        acc1[j] = fmaf(a.y, w[j], acc1[j]);
      }
    }
  }
  { // K tail: k = 128
    float a0 = sm.u.a.At[128][ln2], a1 = sm.u.a.At[128][ln2 + 1];
    const float* wt = WT + (size_t)128 * outc + colOff + lc * 8;
    #pragma unroll
    for (int j = 0; j < 8; j++) {
      float w = wt[j];
      acc0[j] = fmaf(a0, w, acc0[j]);
      acc1[j] = fmaf(a1, w, acc1[j]);
    }
  }
  __syncthreads();   // done with At/Wc; reuse as Y
  #pragma unroll
  for (int j = 0; j < 8; j++) {
    float bb = bias[colOff + lc * 8 + j];
    sm.u.Y[ln2][lc * 8 + j]     = acc0[j] + bb;
    sm.u.Y[ln2 + 1][lc * 8 + j] = acc1[j] + bb;
  }
  __syncthreads();

  if constexpr (EPI == 0) {           // LayerNorm + ReLU + lift
    if (tid < 32) {
      int n = node0 + tid;
      float* Yr = sm.u.Y[tid];
      float s = 0.f, s2 = 0.f;
      for (int i = 0; i < 128; i++) { float v = Yr[i]; s += v; s2 += v * v; }
      float mu = s * (1.f / 128.f);
      float var = s2 * (1.f / 128.f) - mu * mu;
      float rstd = 1.f / sqrtf(var + 1e-5f);
      float ss = 0.f;
      float* orow = out0 + (size_t)n * SD;
      for (int i = 0; i < 128; i++) {
        float z = (Yr[i] - mu) * rstd * g[i] + bv[i];
        z = fmaxf(z, 0.f);
        ss += z * z;
        orow[1 + i] = z;
      }
      orow[0] = sqrtf(1.f + ss);
    }
  } else if constexpr (EPI == 1) {    // per-head lift -> space + time arrays
    float* sp = cb == 0 ? qo.sp0 : (cb == 1 ? qo.sp1 : qo.sp2);
    float* tp = cb == 0 ? qo.tp0 : (cb == 1 ? qo.tp1 : qo.tp2);
    if (tid < 128) {
      int nl = tid >> 2, h = tid & 3;
      float ss = 0.f;
      #pragma unroll
      for (int o = 0; o < 32; o++) { float v = sm.u.Y[nl][(h << 5) + o]; ss += v * v; }
      tp[(size_t)(node0 + nl) * 4 + h] = sqrtf(1.f + ss);
    }
    for (int i = tid; i < 4096; i += 256) {
      int nl = i >> 7, c = i & 127;
      sp[(size_t)(node0 + nl) * 128 + c] = sm.u.Y[nl][c];
    }
  } else if constexpr (EPI == 2) {    // lift + midpoint2(res) + LayerNorm + lift
    if (tid < 32) {
      int n = node0 + tid;
      float* Yr = sm.u.Y[tid];
      const float* rr = res + (size_t)n * SD;
      float sy = 0.f;
      for (int i = 0; i < 128; i++) sy += Yr[i] * Yr[i];
      float t_att = sqrtf(1.f + sy);
      float a0 = 0.5f * (t_att + rr[0]);
      float sa = 0.f, su = 0.f;
      for (int i = 0; i < 128; i++) {
        float a = 0.5f * (Yr[i] + rr[1 + i]);
        Yr[i] = a;
        sa += a * a;
        su += a;
      }
      float den = sqrtf(fmaxf(fabsf(a0 * a0 - sa), 1e-8f));
      float inv = 1.f / den;
      float mu = su * inv * (1.f / 128.f);
      float var = sa * inv * inv * (1.f / 128.f) - mu * mu;
      float rstd = 1.f / sqrtf(var + 1e-5f);
      float ss = 0.f;
      float* orow = out0 + (size_t)n * SD;
      for (int i = 0; i < 128; i++) {
        float z = (Yr[i] * inv - mu) * rstd * g[i] + bv[i];
        ss += z * z;
        orow[1 + i] = z;
      }
      orow[0] = sqrtf(1.f + ss);
    }
  } else {                            // EPI == 3: lift + logmap0 (packed 128-stride out)
    if (tid < 32) {
      float* Yr = sm.u.Y[tid];
      float s = 0.f;
      for (int i = 0; i < 128; i++) s += Yr[i] * Yr[i];
      float nn = sqrtf(fmaxf(s, 1e-12f));
      float t0 = sqrtf(1.f + s);
      float al = fmaxf(t0, 1.f + 1e-7f);
      sm.sc[tid] = acoshf(al) / nn;
    }
    __syncthreads();
    for (int i = tid; i < 4096; i += 256) {
      int nl = i >> 7, c = i & 127;
      out0[(size_t)(node0 + nl) * 128 + c] = sm.u.Y[nl][c] * sm.sc[nl];
    }
  }
}

// =================== edge scores ===================
// thread per (csr position, head)
__global__ void score_kernel(const int* __restrict__ s_csr, const int* __restrict__ d_csr,
                             const int* __restrict__ e_csr,
                             const float* __restrict__ qs, const float* __restrict__ qt,
                             const float* __restrict__ ks, const float* __restrict__ kt,
                             const float* __restrict__ ef, const float* __restrict__ ebw,
                             float* __restrict__ scores) {
  int gid = blockIdx.x * 256 + threadIdx.x;
  int p = gid >> 2, h = gid & 3;
  if (p >= NE) return;
  int s = s_csr[p], d = d_csr[p], e = e_csr[p];
  const float4* qp = (const float4*)(qs + (size_t)d * 128 + h * 32);
  const float4* kp = (const float4*)(ks + (size_t)s * 128 + h * 32);
  float acc = 0.f;
  #pragma unroll
  for (int i = 0; i < 8; i++) {
    float4 a = qp[i], b = kp[i];
    acc += a.x * b.x + a.y * b.y + a.z * b.z + a.w * b.w;
  }
  acc -= qt[(size_t)d * 4 + h] * kt[(size_t)s * 4 + h];
  float sc = (2.0f + 2.0f * acc) * 0.17677669529663687f;   // 1/sqrt(32)
  const float4* ep = (const float4*)(ef + (size_t)e * 16);
  const float4* bp = (const float4*)(ebw + h * 16);
  #pragma unroll
  for (int i = 0; i < 4; i++) {
    float4 a = ep[i], b = bp[i];
    sc += a.x * b.x + a.y * b.y + a.z * b.z + a.w * b.w;
  }
  scores[(size_t)p * 4 + h] = sc;
}

// =================== softmax + aggregation + normalize + lift ===================
// 4 nodes per 256-thread block; one wave per node; all cross-lane via shuffles
// lane = (head h = lane/16, dim-pair d2 = lane%16)
__global__ void __launch_bounds__(256) agg_kernel(const int* __restrict__ ro,
                                                  const int* __restrict__ s_csr,
                                                  const float* __restrict__ scores,
                                                  const float* __restrict__ vs,
                                                  const float* __restrict__ vt,
                                                  float* __restrict__ agg) {
  int n = blockIdx.x * 4 + (threadIdx.x >> 6);
  if (n >= NN) return;
  int lane = threadIdx.x & 63;
  int h = lane >> 4, d2 = lane & 15;
  int r0 = ro[n], r1 = ro[n + 1];
  int deg = r1 - r0;

  float m = -INFINITY;
  for (int j = d2; j < deg; j += 16) m = fmaxf(m, scores[(size_t)(r0 + j) * 4 + h]);
  m = fmaxf(m, __shfl_xor(m, 1));
  m = fmaxf(m, __shfl_xor(m, 2));
  m = fmaxf(m, __shfl_xor(m, 4));
  m = fmaxf(m, __shfl_xor(m, 8));

  float acc0 = 0.f, acc1 = 0.f, acct = 0.f, den = 0.f;
  for (int cbase = 0; cbase < deg; cbase += 16) {
    int cnt = min(deg - cbase, 16);
    float myw = (d2 < cnt) ? expf(scores[(size_t)(r0 + cbase + d2) * 4 + h] - m) : 0.f;
    int mysrc = (lane < cnt) ? s_csr[r0 + cbase + lane] : 0;
    for (int j = 0; j < cnt; j++) {
      float w = __shfl(myw, (h << 4) | j);
      int s = __shfl(mysrc, j);
      den += w;
      acc0 += w * vs[(size_t)s * 128 + (h << 5) + d2];
      acc1 += w * vs[(size_t)s * 128 + (h << 5) + 16 + d2];
      if (d2 == 0) acct += w * vt[(size_t)s * 4 + h];
    }
  }
  float inv = 1.f / (den + 1e-16f);
  float a0 = acc0 * inv, a1 = acc1 * inv;
  float at = __shfl(acct, h << 4) * inv;
  float p = a0 * a0 + a1 * a1;
  p += __shfl_xor(p, 1);
  p += __shfl_xor(p, 2);
  p += __shfl_xor(p, 4);
  p += __shfl_xor(p, 8);
  float dh = sqrtf(fmaxf(fabsf(at * at - p), 1e-8f));
  float o0 = a0 / dh, o1 = a1 / dh;
  float q = o0 * o0 + o1 * o1;
  q += __shfl_xor(q, 1);
  q += __shfl_xor(q, 2);
  q += __shfl_xor(q, 4);
  q += __shfl_xor(q, 8);
  q += __shfl_xor(q, 16);
  q += __shfl_xor(q, 32);
  float* ar = agg + (size_t)n * SD;
  if (lane == 0) ar[0] = sqrtf(1.f + q);
  ar[1 + (h << 5) + d2] = o0;
  ar[1 + (h << 5) + 16 + d2] = o1;
}

// =================== launch ===================

extern "C" void kernel_launch(void* const* d_in, const int* in_sizes, int n_in,
                              void* d_out, int out_size, void* d_ws, size_t ws_size,
                              hipStream_t stream) {
  const float* x      = (const float*)d_in[0];
  const int*   ei     = (const int*)  d_in[1];
  const float* ef     = (const float*)d_in[2];
  const float* in_w   = (const float*)d_in[3];
  const float* in_b   = (const float*)d_in[4];
  const float* in_g   = (const float*)d_in[5];
  const float* in_bb  = (const float*)d_in[6];
  const float* q_w    = (const float*)d_in[7];
  const float* q_b    = (const float*)d_in[8];
  const float* k_w    = (const float*)d_in[9];
  const float* k_b    = (const float*)d_in[10];
  const float* v_w    = (const float*)d_in[11];
  const float* v_b    = (const float*)d_in[12];
  const float* out_w  = (const float*)d_in[13];
  const float* out_b  = (const float*)d_in[14];
  const float* eb_w   = (const float*)d_in[15];
  const float* norm_g = (const float*)d_in[16];
  const float* norm_b = (const float*)d_in[17];
  const float* outp_w = (const float*)d_in[18];
  const float* outp_b = (const float*)d_in[19];

  const int* srcI = ei;
  const int* dstI = ei + NE;

  // ---- carve workspace ----
  char* base = (char*)d_ws;
  size_t off = 0;
  auto carve = [&](size_t bytes) -> char* {
    char* p = base + off;
    off = (off + bytes + 255) & ~(size_t)255;
    return p;
  };
  float* buf0   = (float*)carve((size_t)NN * SD * 4);
  float* buf1   = (float*)carve((size_t)NN * SD * 4);
  float* qs     = (float*)carve((size_t)NN * 128 * 4);
  float* qt     = (float*)carve((size_t)NN * 4 * 4);
  float* ks     = (float*)carve((size_t)NN * 128 * 4);
  float* kt     = (float*)carve((size_t)NN * 4 * 4);
  float* vs     = (float*)carve((size_t)NN * 128 * 4);
  float* vt     = (float*)carve((size_t)NN * 4 * 4);
  float* scores = (float*)carve((size_t)NE * 4 * 4);
  int*   s_csr  = (int*)  carve((size_t)NE * 4);
  int*   d_csr  = (int*)  carve((size_t)NE * 4);
  int*   e_csr  = (int*)  carve((size_t)NE * 4);
  int*   ro     = (int*)  carve((size_t)(NN + 1) * 4);
  int*   counts = (int*)  carve((size_t)NN * 4);
  float* WT     = (float*)carve((size_t)WT_TOTAL * 4);
  float* bq     = (float*)carve((size_t)768 * 4);
  if (off > ws_size) return;  // workspace too small; bail

  QkvPtrs qkvp{qs, qt, ks, kt, vs, vt};
  QkvPtrs qz{nullptr, nullptr, nullptr, nullptr, nullptr, nullptr};

  // ---- weight prep ----
  prep_wt<<<(KD * 1280 + 255) / 256, 256, 0, stream>>>(in_w, q_w, k_w, v_w, out_w, outp_w, WT);
  prep_bias<<<3, 256, 0, stream>>>(q_b, k_b, v_b, bq);

  // ---- CSR build (by dst) ----
  zero_i32<<<(NN + 255) / 256, 256, 0, stream>>>(counts, NN);
  count_kernel<<<NE / 256, 256, 0, stream>>>(dstI, counts, NE);
  scan_kernel<<<1, 1024, 0, stream>>>(counts, ro, NN);
  zero_i32<<<(NN + 255) / 256, 256, 0, stream>>>(counts, NN);
  scatter_kernel<<<NE / 256, 256, 0, stream>>>(srcI, dstI, ro, counts, s_csr, d_csr, e_csr, NE);

  // ---- input embedding ----
  expmap_kernel<<<NN / 4, 256, 0, stream>>>(x, buf0);
  node_gemm<0><<<dim3(NN / 32, 1), 256, 0, stream>>>(buf0, WT + OFF_IN, 128, in_b, buf0, qz,
                                                     nullptr, in_g, in_bb);

  // ---- layers ----
  float* hcur = buf0;
  float* hoth = buf1;
  for (int l = 0; l < 2; l++) {
    node_gemm<1><<<dim3(NN / 32, 3), 256, 0, stream>>>(
        hcur, WT + (l ? OFF_QKV1 : OFF_QKV0), 384, bq + l * 384, nullptr, qkvp,
        nullptr, nullptr, nullptr);
    score_kernel<<<NE * 4 / 256, 256, 0, stream>>>(s_csr, d_csr, e_csr, qs, qt, ks, kt,
                                                   ef, eb_w + l * 64, scores);
    agg_kernel<<<NN / 4, 256, 0, stream>>>(ro, s_csr, scores, vs, vt, hoth);
    node_gemm<2><<<dim3(NN / 32, 1), 256, 0, stream>>>(
        hoth, WT + (l ? OFF_OUT1 : OFF_OUT0), 128, out_b + l * 128, hoth, qz,
        hcur, norm_g + l * 128, norm_b + l * 128);
    float* tmp = hcur; hcur = hoth; hoth = tmp;
  }

  // ---- output projection + logmap ----
  node_gemm<3><<<dim3(NN / 32, 1), 256, 0, stream>>>(hcur, WT + OFF_OUTP, 128, outp_b,
                                                     (float*)d_out, qz, nullptr, nullptr, nullptr);
}

// Round 3
// 765.672 us; speedup vs baseline: 1.1795x; 1.1795x over previous
//
#include <hip/hip_runtime.h>
#include <math.h>

constexpr int NN = 40000;
constexpr int NE = 640000;
constexpr int KD = 129;     // contraction dim (time + 128 space)
constexpr int SD = 132;     // state row stride (16B-aligned)

// ---- transposed-weight buffer offsets (in floats) ----
constexpr int OFF_IN   = 0;
constexpr int OFF_QKV0 = OFF_IN   + KD*128;
constexpr int OFF_QKV1 = OFF_QKV0 + KD*384;
constexpr int OFF_OUT0 = OFF_QKV1 + KD*384;
constexpr int OFF_OUT1 = OFF_OUT0 + KD*128;
constexpr int OFF_OUTP = OFF_OUT1 + KD*128;
constexpr int WT_TOTAL = OFF_OUTP + KD*128;   // 165120 floats

struct QkvPtrs {
  float* sp0; float* tp0;
  float* sp1; float* tp1;
  float* sp2; float* tp2;
};

// =================== small utility kernels ===================

__global__ void zero_i32(int* p, int n) {
  int i = blockIdx.x * 256 + threadIdx.x;
  if (i < n) p[i] = 0;
}

// transpose all weights to k-major once per call
__global__ void prep_wt(const float* __restrict__ in_w, const float* __restrict__ q_w,
                        const float* __restrict__ k_w, const float* __restrict__ v_w,
                        const float* __restrict__ out_w, const float* __restrict__ outp_w,
                        float* __restrict__ WT) {
  int t = blockIdx.x * 256 + threadIdx.x;
  if (t >= KD * 1280) return;
  int k = t / 1280, c = t % 1280;
  float v; int dst;
  if (c < 128) {
    v = in_w[(size_t)c * KD + k];
    dst = OFF_IN + k * 128 + c;
  } else if (c < 896) {
    int l = (c - 128) / 384, cc = (c - 128) % 384;
    int arr = cc >> 7, r = cc & 127;
    const float* w = arr == 0 ? q_w : (arr == 1 ? k_w : v_w);
    v = w[((size_t)l * 128 + r) * KD + k];
    dst = (l == 0 ? OFF_QKV0 : OFF_QKV1) + k * 384 + cc;
  } else if (c < 1152) {
    int l = (c - 896) / 128, r = (c - 896) % 128;
    v = out_w[((size_t)l * 128 + r) * KD + k];
    dst = (l == 0 ? OFF_OUT0 : OFF_OUT1) + k * 128 + r;
  } else {
    int r = c - 1152;
    v = outp_w[(size_t)r * KD + k];
    dst = OFF_OUTP + k * 128 + r;
  }
  WT[dst] = v;
}

__global__ void prep_bias(const float* __restrict__ q_b, const float* __restrict__ k_b,
                          const float* __restrict__ v_b, float* __restrict__ bq) {
  int t = blockIdx.x * 256 + threadIdx.x;
  if (t >= 768) return;
  int l = t / 384, c = t % 384;
  int arr = c >> 7, r = c & 127;
  const float* b = arr == 0 ? q_b : (arr == 1 ? k_b : v_b);
  bq[t] = b[l * 128 + r];
}

// =================== CSR build ===================

__global__ void count_kernel(const int* __restrict__ dst, int* __restrict__ counts, int E) {
  int e = blockIdx.x * 256 + threadIdx.x;
  if (e < E) atomicAdd(&counts[dst[e]], 1);
}

__global__ void __launch_bounds__(1024) scan_kernel(const int* __restrict__ counts,
                                                    int* __restrict__ ro, int n) {
  __shared__ int wsum[16];
  __shared__ int carry;
  int tid = threadIdx.x, wid = tid >> 6, lane = tid & 63;
  if (tid == 0) { carry = 0; ro[0] = 0; }
  __syncthreads();
  for (int base = 0; base < n; base += 1024) {
    int idx = base + tid;
    int v = (idx < n) ? counts[idx] : 0;
    int s = v;
    #pragma unroll
    for (int off = 1; off < 64; off <<= 1) {
      int t = __shfl_up(s, off);
      if (lane >= off) s += t;
    }
    if (lane == 63) wsum[wid] = s;
    __syncthreads();
    if (wid == 0) {
      int ws = (lane < 16) ? wsum[lane] : 0;
      #pragma unroll
      for (int off = 1; off < 16; off <<= 1) {
        int t = __shfl_up(ws, off);
        if (lane >= off) ws += t;
      }
      if (lane < 16) wsum[lane] = ws;
    }
    __syncthreads();
    int woff = (wid > 0) ? wsum[wid - 1] : 0;
    if (idx < n) ro[idx + 1] = s + woff + carry;
    int total = wsum[15];
    __syncthreads();
    if (tid == 0) carry += total;
    __syncthreads();
  }
}

// also emits inv_e: CSR position of each original edge id
__global__ void scatter_kernel(const int* __restrict__ src, const int* __restrict__ dst,
                               const int* __restrict__ ro, int* __restrict__ cursor,
                               int* __restrict__ s_csr, int* __restrict__ inv_e, int E) {
  int e = blockIdx.x * 256 + threadIdx.x;
  if (e >= E) return;
  int d = dst[e];
  int pos = ro[d] + atomicAdd(&cursor[d], 1);
  s_csr[pos] = src[e];
  inv_e[e] = pos;
}

// =================== edge-bias precompute (both layers, CSR-ordered out) ===================
// eb_w layout: [2][4][16] = 128 floats
__global__ __launch_bounds__(256) void ebias_kernel(const float* __restrict__ ef,
                                                    const float* __restrict__ ebw,
                                                    const int* __restrict__ inv_e,
                                                    float* __restrict__ eb) {
  __shared__ float w[128];
  if (threadIdx.x < 128) w[threadIdx.x] = ebw[threadIdx.x];
  __syncthreads();
  int e = blockIdx.x * 256 + threadIdx.x;
  if (e >= NE) return;
  float f[16];
  #pragma unroll
  for (int i = 0; i < 4; i++) *(float4*)&f[i * 4] = *(const float4*)(ef + (size_t)e * 16 + i * 4);
  int pos = inv_e[e];
  #pragma unroll
  for (int l = 0; l < 2; l++) {
    float4 o;
    float* op = &o.x;
    #pragma unroll
    for (int h = 0; h < 4; h++) {
      float acc = 0.f;
      #pragma unroll
      for (int i = 0; i < 16; i++) acc = fmaf(f[i], w[l * 64 + h * 16 + i], acc);
      op[h] = acc;
    }
    *(float4*)(eb + (size_t)l * NE * 4 + (size_t)pos * 4) = o;
  }
}

// =================== expmap0 ===================
// block = 256 = 4 nodes x 64 lanes
__global__ void expmap_kernel(const float* __restrict__ x, float* __restrict__ h) {
  int nl = threadIdx.x >> 6, lane = threadIdx.x & 63;
  int n = blockIdx.x * 4 + nl;
  if (n >= NN) return;
  const float* xr = x + (size_t)n * 128;
  float v0 = xr[lane], v1 = xr[lane + 64];
  float ss = v0 * v0 + v1 * v1;
  #pragma unroll
  for (int off = 1; off < 64; off <<= 1) ss += __shfl_xor(ss, off);
  float nn = sqrtf(fmaxf(ss, 1e-12f));
  float s = sinhf(nn) / nn;
  float* hr = h + (size_t)n * SD;
  if (lane == 0) hr[0] = coshf(nn);
  hr[1 + lane] = s * v0;
  hr[1 + lane + 64] = s * v1;
}

// =================== fused node GEMM ===================
// 32 nodes x 128 cols per block; 256 threads; thread = (ln 0..15, lc 0..15)
// each thread: 2 nodes (2*ln, 2*ln+1) x 8 cols (lc*8 .. lc*8+7)
struct SMem {
  union {
    struct { float At[KD][32]; float Wc[32][144]; } a;  // 34944 B
    float Y[32][132];                                   // 16896 B
  } u;
  float sc[32];
};

// EPI: 0 = LN+ReLU+lift (in-proj), 1 = per-head lift (qkv),
//      2 = lift+midpoint+LN+lift (out-proj), 3 = lift+logmap0 (final)
template<int EPI>
__global__ __launch_bounds__(256) void node_gemm(
    const float* A, const float* __restrict__ WT, int outc,
    const float* __restrict__ bias, float* out0, QkvPtrs qo,
    const float* __restrict__ res, const float* __restrict__ g,
    const float* __restrict__ bv) {
  __shared__ SMem sm;
  const int tid = threadIdx.x;
  const int lc = tid & 15, ln = tid >> 4;
  const int ln2 = ln << 1;
  const int node0 = blockIdx.x * 32;
  const int cb = blockIdx.y;
  const int colOff = cb << 7;

  // A-tile, transposed: At[k][node]; float4 global loads, conflict-free stores
  for (int idx = tid; idx < 32 * 33; idx += 256) {
    int nl = idx & 31, c = idx >> 5;
    const float* ar = A + (size_t)(node0 + nl) * SD;
    if (c < 32) {
      float4 v = *(const float4*)(ar + (c << 2));
      int k = c << 2;
      sm.u.a.At[k][nl] = v.x;
      sm.u.a.At[k + 1][nl] = v.y;
      sm.u.a.At[k + 2][nl] = v.z;
      sm.u.a.At[k + 3][nl] = v.w;
    } else {
      sm.u.a.At[128][nl] = ar[128];
    }
  }
  float acc0[8], acc1[8];
  #pragma unroll
  for (int j = 0; j < 8; j++) { acc0[j] = 0.f; acc1[j] = 0.f; }
  const int wb = (lc >> 2) * 36 + ((lc & 3) << 3);

  for (int kc = 0; kc < 128; kc += 32) {
    __syncthreads();
    #pragma unroll
    for (int i = tid; i < 1024; i += 256) {   // stage W chunk [32][128] -> padded groups
      int kk = i >> 5, c4 = (i & 31) << 2;
      float4 w = *(const float4*)(WT + (size_t)(kc + kk) * outc + colOff + c4);
      *(float4*)&sm.u.a.Wc[kk][(c4 >> 5) * 36 + (c4 & 31)] = w;
    }
    __syncthreads();
    #pragma unroll 8
    for (int kk = 0; kk < 32; ++kk) {
      const float2 a = *(const float2*)&sm.u.a.At[kc + kk][ln2];
      const float* wr = &sm.u.a.Wc[kk][wb];
      float w[8];
      *(float4*)&w[0] = *(const float4*)wr;
      *(float4*)&w[4] = *(const float4*)(wr + 4);
      #pragma unroll
      for (int j = 0; j < 8; j++) {
        acc0[j] = fmaf(a.x, w[j], acc0[j]);
        acc1[j] = fmaf(a.y, w[j], acc1[j]);
      }
    }
  }
  { // K tail: k = 128
    float a0 = sm.u.a.At[128][ln2], a1 = sm.u.a.At[128][ln2 + 1];
    const float* wt = WT + (size_t)128 * outc + colOff + lc * 8;
    #pragma unroll
    for (int j = 0; j < 8; j++) {
      float w = wt[j];
      acc0[j] = fmaf(a0, w, acc0[j]);
      acc1[j] = fmaf(a1, w, acc1[j]);
    }
  }
  __syncthreads();   // done with At/Wc; reuse as Y
  #pragma unroll
  for (int j = 0; j < 8; j++) {
    float bb = bias[colOff + lc * 8 + j];
    sm.u.Y[ln2][lc * 8 + j]     = acc0[j] + bb;
    sm.u.Y[ln2 + 1][lc * 8 + j] = acc1[j] + bb;
  }
  __syncthreads();

  if constexpr (EPI == 0) {           // LayerNorm + ReLU + lift
    if (tid < 32) {
      int n = node0 + tid;
      float* Yr = sm.u.Y[tid];
      float s = 0.f, s2 = 0.f;
      for (int i = 0; i < 128; i++) { float v = Yr[i]; s += v; s2 += v * v; }
      float mu = s * (1.f / 128.f);
      float var = s2 * (1.f / 128.f) - mu * mu;
      float rstd = 1.f / sqrtf(var + 1e-5f);
      float ss = 0.f;
      float* orow = out0 + (size_t)n * SD;
      for (int i = 0; i < 128; i++) {
        float z = (Yr[i] - mu) * rstd * g[i] + bv[i];
        z = fmaxf(z, 0.f);
        ss += z * z;
        orow[1 + i] = z;
      }
      orow[0] = sqrtf(1.f + ss);
    }
  } else if constexpr (EPI == 1) {    // per-head lift -> space + time arrays
    float* sp = cb == 0 ? qo.sp0 : (cb == 1 ? qo.sp1 : qo.sp2);
    float* tp = cb == 0 ? qo.tp0 : (cb == 1 ? qo.tp1 : qo.tp2);
    if (tid < 128) {
      int nl = tid >> 2, h = tid & 3;
      float ss = 0.f;
      #pragma unroll
      for (int o = 0; o < 32; o++) { float v = sm.u.Y[nl][(h << 5) + o]; ss += v * v; }
      tp[(size_t)(node0 + nl) * 4 + h] = sqrtf(1.f + ss);
    }
    for (int i = tid; i < 4096; i += 256) {
      int nl = i >> 7, c = i & 127;
      sp[(size_t)(node0 + nl) * 128 + c] = sm.u.Y[nl][c];
    }
  } else if constexpr (EPI == 2) {    // lift + midpoint2(res) + LayerNorm + lift
    if (tid < 32) {
      int n = node0 + tid;
      float* Yr = sm.u.Y[tid];
      const float* rr = res + (size_t)n * SD;
      float sy = 0.f;
      for (int i = 0; i < 128; i++) sy += Yr[i] * Yr[i];
      float t_att = sqrtf(1.f + sy);
      float a0 = 0.5f * (t_att + rr[0]);
      float sa = 0.f, su = 0.f;
      for (int i = 0; i < 128; i++) {
        float a = 0.5f * (Yr[i] + rr[1 + i]);
        Yr[i] = a;
        sa += a * a;
        su += a;
      }
      float den = sqrtf(fmaxf(fabsf(a0 * a0 - sa), 1e-8f));
      float inv = 1.f / den;
      float mu = su * inv * (1.f / 128.f);
      float var = sa * inv * inv * (1.f / 128.f) - mu * mu;
      float rstd = 1.f / sqrtf(var + 1e-5f);
      float ss = 0.f;
      float* orow = out0 + (size_t)n * SD;
      for (int i = 0; i < 128; i++) {
        float z = (Yr[i] * inv - mu) * rstd * g[i] + bv[i];
        ss += z * z;
        orow[1 + i] = z;
      }
      orow[0] = sqrtf(1.f + ss);
    }
  } else {                            // EPI == 3: lift + logmap0 (packed 128-stride out)
    if (tid < 32) {
      float* Yr = sm.u.Y[tid];
      float s = 0.f;
      for (int i = 0; i < 128; i++) s += Yr[i] * Yr[i];
      float nn = sqrtf(fmaxf(s, 1e-12f));
      float t0 = sqrtf(1.f + s);
      float al = fmaxf(t0, 1.f + 1e-7f);
      sm.sc[tid] = acoshf(al) / nn;
    }
    __syncthreads();
    for (int i = tid; i < 4096; i += 256) {
      int nl = i >> 7, c = i & 127;
      out0[(size_t)(node0 + nl) * 128 + c] = sm.u.Y[nl][c] * sm.sc[nl];
    }
  }
}

// =================== fused edge attention (score + online softmax + aggregate) ===================
// 4 nodes per 256-thread block; one wave per node; lane = (head h = lane/16, d2 = lane%16)
__global__ __launch_bounds__(256) void edge_attn_kernel(const int* __restrict__ ro,
                                                        const int* __restrict__ s_csr,
                                                        const float* __restrict__ ebias,
                                                        const float* __restrict__ qs,
                                                        const float* __restrict__ qt,
                                                        const float* __restrict__ ks,
                                                        const float* __restrict__ kt,
                                                        const float* __restrict__ vs,
                                                        const float* __restrict__ vt,
                                                        float* __restrict__ agg) {
  int n = blockIdx.x * 4 + (threadIdx.x >> 6);
  if (n >= NN) return;
  int lane = threadIdx.x & 63;
  int h = lane >> 4, d2 = lane & 15;
  int r0 = ro[n], deg = ro[n + 1] - r0;

  int qoff = n * 128 + (h << 5) + d2;
  float q0 = qs[qoff], q1 = qs[qoff + 16];
  float qth = qt[(size_t)n * 4 + h];

  float m = -1e30f, den = 0.f, acc0 = 0.f, acc1 = 0.f, acct = 0.f;

  // pipeline regs (next edge)
  int   sN = 0;
  float k0N = 0, k1N = 0, ktN = 0, v0N = 0, v1N = 0, vtN = 0, ebN = 0;
  if (deg > 0) {
    sN = s_csr[r0];
    int so = sN * 128 + (h << 5) + d2;
    k0N = ks[so]; k1N = ks[so + 16];
    v0N = vs[so]; v1N = vs[so + 16];
    ktN = kt[(size_t)sN * 4 + h];
    vtN = vt[(size_t)sN * 4 + h];
    ebN = ebias[(size_t)r0 * 4 + h];
  }
  int s1 = (deg > 1) ? s_csr[r0 + 1] : 0;

  for (int j = 0; j < deg; j++) {
    float k0 = k0N, k1 = k1N, ktc = ktN, v0 = v0N, v1 = v1N, vtc = vtN, eb = ebN;
    // prefetch j+1 (s already resident), fetch s for j+2
    if (j + 1 < deg) {
      int so = s1 * 128 + (h << 5) + d2;
      k0N = ks[so]; k1N = ks[so + 16];
      v0N = vs[so]; v1N = vs[so + 16];
      ktN = kt[(size_t)s1 * 4 + h];
      vtN = vt[(size_t)s1 * 4 + h];
      ebN = ebias[(size_t)(r0 + j + 1) * 4 + h];
    }
    if (j + 2 < deg) s1 = s_csr[r0 + j + 2];

    float dp = q0 * k0 + q1 * k1;
    dp += __shfl_xor(dp, 1);
    dp += __shfl_xor(dp, 2);
    dp += __shfl_xor(dp, 4);
    dp += __shfl_xor(dp, 8);
    float sc = (2.f + 2.f * (dp - qth * ktc)) * 0.17677669529663687f + eb;

    float mN = fmaxf(m, sc);
    float scale = expf(m - mN);
    float w = expf(sc - mN);
    den  = den  * scale + w;
    acc0 = acc0 * scale + w * v0;
    acc1 = acc1 * scale + w * v1;
    acct = acct * scale + w * vtc;
    m = mN;
  }

  float inv = 1.f / (den + 1e-16f);
  float a0 = acc0 * inv, a1 = acc1 * inv;
  float at = acct * inv;
  float p = a0 * a0 + a1 * a1;
  p += __shfl_xor(p, 1);
  p += __shfl_xor(p, 2);
  p += __shfl_xor(p, 4);
  p += __shfl_xor(p, 8);
  float dh = sqrtf(fmaxf(fabsf(at * at - p), 1e-8f));
  float o0 = a0 / dh, o1 = a1 / dh;
  float q = o0 * o0 + o1 * o1;
  q += __shfl_xor(q, 1);
  q += __shfl_xor(q, 2);
  q += __shfl_xor(q, 4);
  q += __shfl_xor(q, 8);
  q += __shfl_xor(q, 16);
  q += __shfl_xor(q, 32);
  float* ar = agg + (size_t)n * SD;
  if (lane == 0) ar[0] = sqrtf(1.f + q);
  ar[1 + (h << 5) + d2] = o0;
  ar[1 + (h << 5) + 16 + d2] = o1;
}

// =================== launch ===================

extern "C" void kernel_launch(void* const* d_in, const int* in_sizes, int n_in,
                              void* d_out, int out_size, void* d_ws, size_t ws_size,
                              hipStream_t stream) {
  const float* x      = (const float*)d_in[0];
  const int*   ei     = (const int*)  d_in[1];
  const float* ef     = (const float*)d_in[2];
  const float* in_w   = (const float*)d_in[3];
  const float* in_b   = (const float*)d_in[4];
  const float* in_g   = (const float*)d_in[5];
  const float* in_bb  = (const float*)d_in[6];
  const float* q_w    = (const float*)d_in[7];
  const float* q_b    = (const float*)d_in[8];
  const float* k_w    = (const float*)d_in[9];
  const float* k_b    = (const float*)d_in[10];
  const float* v_w    = (const float*)d_in[11];
  const float* v_b    = (const float*)d_in[12];
  const float* out_w  = (const float*)d_in[13];
  const float* out_b  = (const float*)d_in[14];
  const float* eb_w   = (const float*)d_in[15];
  const float* norm_g = (const float*)d_in[16];
  const float* norm_b = (const float*)d_in[17];
  const float* outp_w = (const float*)d_in[18];
  const float* outp_b = (const float*)d_in[19];

  const int* srcI = ei;
  const int* dstI = ei + NE;

  // ---- carve workspace ----
  char* base = (char*)d_ws;
  size_t off = 0;
  auto carve = [&](size_t bytes) -> char* {
    char* p = base + off;
    off = (off + bytes + 255) & ~(size_t)255;
    return p;
  };
  float* buf0   = (float*)carve((size_t)NN * SD * 4);
  float* buf1   = (float*)carve((size_t)NN * SD * 4);
  float* qs     = (float*)carve((size_t)NN * 128 * 4);
  float* qt     = (float*)carve((size_t)NN * 4 * 4);
  float* ks     = (float*)carve((size_t)NN * 128 * 4);
  float* kt     = (float*)carve((size_t)NN * 4 * 4);
  float* vs     = (float*)carve((size_t)NN * 128 * 4);
  float* vt     = (float*)carve((size_t)NN * 4 * 4);
  float* ebias  = (float*)carve((size_t)2 * NE * 4 * 4);
  int*   s_csr  = (int*)  carve((size_t)NE * 4);
  int*   inv_e  = (int*)  carve((size_t)NE * 4);
  int*   ro     = (int*)  carve((size_t)(NN + 1) * 4);
  int*   counts = (int*)  carve((size_t)NN * 4);
  float* WT     = (float*)carve((size_t)WT_TOTAL * 4);
  float* bq     = (float*)carve((size_t)768 * 4);
  if (off > ws_size) return;  // workspace too small; bail

  QkvPtrs qkvp{qs, qt, ks, kt, vs, vt};
  QkvPtrs qz{nullptr, nullptr, nullptr, nullptr, nullptr, nullptr};

  // ---- weight prep ----
  prep_wt<<<(KD * 1280 + 255) / 256, 256, 0, stream>>>(in_w, q_w, k_w, v_w, out_w, outp_w, WT);
  prep_bias<<<3, 256, 0, stream>>>(q_b, k_b, v_b, bq);

  // ---- CSR build (by dst) ----
  zero_i32<<<(NN + 255) / 256, 256, 0, stream>>>(counts, NN);
  count_kernel<<<NE / 256, 256, 0, stream>>>(dstI, counts, NE);
  scan_kernel<<<1, 1024, 0, stream>>>(counts, ro, NN);
  zero_i32<<<(NN + 255) / 256, 256, 0, stream>>>(counts, NN);
  scatter_kernel<<<NE / 256, 256, 0, stream>>>(srcI, dstI, ro, counts, s_csr, inv_e, NE);

  // ---- edge biases for both layers (CSR-ordered) ----
  ebias_kernel<<<(NE + 255) / 256, 256, 0, stream>>>(ef, eb_w, inv_e, ebias);

  // ---- input embedding ----
  expmap_kernel<<<NN / 4, 256, 0, stream>>>(x, buf0);
  node_gemm<0><<<dim3(NN / 32, 1), 256, 0, stream>>>(buf0, WT + OFF_IN, 128, in_b, buf0, qz,
                                                     nullptr, in_g, in_bb);

  // ---- layers ----
  float* hcur = buf0;
  float* hoth = buf1;
  for (int l = 0; l < 2; l++) {
    node_gemm<1><<<dim3(NN / 32, 3), 256, 0, stream>>>(
        hcur, WT + (l ? OFF_QKV1 : OFF_QKV0), 384, bq + l * 384, nullptr, qkvp,
        nullptr, nullptr, nullptr);
    edge_attn_kernel<<<NN / 4, 256, 0, stream>>>(ro, s_csr, ebias + (size_t)l * NE * 4,
                                                 qs, qt, ks, kt, vs, vt, hoth);
    node_gemm<2><<<dim3(NN / 32, 1), 256, 0, stream>>>(
        hoth, WT + (l ? OFF_OUT1 : OFF_OUT0), 128, out_b + l * 128, hoth, qz,
        hcur, norm_g + l * 128, norm_b + l * 128);
    float* tmp = hcur; hcur = hoth; hoth = tmp;
  }

  // ---- output projection + logmap ----
  node_gemm<3><<<dim3(NN / 32, 1), 256, 0, stream>>>(hcur, WT + OFF_OUTP, 128, outp_b,
                                                     (float*)d_out, qz, nullptr, nullptr, nullptr);
}

// Round 4
// 675.264 us; speedup vs baseline: 1.3374x; 1.1339x over previous
//
#include <hip/hip_runtime.h>
#include <math.h>

constexpr int NN = 40000;
constexpr int NE = 640000;
constexpr int KD = 129;     // contraction dim (time + 128 space)

// ---- transposed-weight buffer offsets (in floats) ----
constexpr int OFF_IN   = 0;
constexpr int OFF_QKV0 = OFF_IN   + KD*128;
constexpr int OFF_QKV1 = OFF_QKV0 + KD*384;
constexpr int OFF_OUT0 = OFF_QKV1 + KD*384;
constexpr int OFF_OUT1 = OFF_OUT0 + KD*128;
constexpr int OFF_OUTP = OFF_OUT1 + KD*128;
constexpr int WT_TOTAL = OFF_OUTP + KD*128;   // 165120 floats

struct QkvPtrs {
  float* sp0; float* tp0;
  float* sp1; float* tp1;
  float* sp2; float* tp2;
};

// =================== small utility kernels ===================

__global__ void zero_i32(int* p, int n) {
  int i = blockIdx.x * 256 + threadIdx.x;
  if (i < n) p[i] = 0;
}

// transpose all weights to k-major once per call
__global__ void prep_wt(const float* __restrict__ in_w, const float* __restrict__ q_w,
                        const float* __restrict__ k_w, const float* __restrict__ v_w,
                        const float* __restrict__ out_w, const float* __restrict__ outp_w,
                        float* __restrict__ WT) {
  int t = blockIdx.x * 256 + threadIdx.x;
  if (t >= KD * 1280) return;
  int k = t / 1280, c = t % 1280;
  float v; int dst;
  if (c < 128) {
    v = in_w[(size_t)c * KD + k];
    dst = OFF_IN + k * 128 + c;
  } else if (c < 896) {
    int l = (c - 128) / 384, cc = (c - 128) % 384;
    int arr = cc >> 7, r = cc & 127;
    const float* w = arr == 0 ? q_w : (arr == 1 ? k_w : v_w);
    v = w[((size_t)l * 128 + r) * KD + k];
    dst = (l == 0 ? OFF_QKV0 : OFF_QKV1) + k * 384 + cc;
  } else if (c < 1152) {
    int l = (c - 896) / 128, r = (c - 896) % 128;
    v = out_w[((size_t)l * 128 + r) * KD + k];
    dst = (l == 0 ? OFF_OUT0 : OFF_OUT1) + k * 128 + r;
  } else {
    int r = c - 1152;
    v = outp_w[(size_t)r * KD + k];
    dst = OFF_OUTP + k * 128 + r;
  }
  WT[dst] = v;
}

__global__ void prep_bias(const float* __restrict__ q_b, const float* __restrict__ k_b,
                          const float* __restrict__ v_b, float* __restrict__ bq) {
  int t = blockIdx.x * 256 + threadIdx.x;
  if (t >= 768) return;
  int l = t / 384, c = t % 384;
  int arr = c >> 7, r = c & 127;
  const float* b = arr == 0 ? q_b : (arr == 1 ? k_b : v_b);
  bq[t] = b[l * 128 + r];
}

// =================== CSR build ===================

__global__ void count_kernel(const int* __restrict__ dst, int* __restrict__ counts, int E) {
  int e = blockIdx.x * 256 + threadIdx.x;
  if (e < E) atomicAdd(&counts[dst[e]], 1);
}

__global__ void __launch_bounds__(1024) scan_kernel(const int* __restrict__ counts,
                                                    int* __restrict__ ro, int n) {
  __shared__ int wsum[16];
  __shared__ int carry;
  int tid = threadIdx.x, wid = tid >> 6, lane = tid & 63;
  if (tid == 0) { carry = 0; ro[0] = 0; }
  __syncthreads();
  for (int base = 0; base < n; base += 1024) {
    int idx = base + tid;
    int v = (idx < n) ? counts[idx] : 0;
    int s = v;
    #pragma unroll
    for (int off = 1; off < 64; off <<= 1) {
      int t = __shfl_up(s, off);
      if (lane >= off) s += t;
    }
    if (lane == 63) wsum[wid] = s;
    __syncthreads();
    if (wid == 0) {
      int ws = (lane < 16) ? wsum[lane] : 0;
      #pragma unroll
      for (int off = 1; off < 16; off <<= 1) {
        int t = __shfl_up(ws, off);
        if (lane >= off) ws += t;
      }
      if (lane < 16) wsum[lane] = ws;
    }
    __syncthreads();
    int woff = (wid > 0) ? wsum[wid - 1] : 0;
    if (idx < n) ro[idx + 1] = s + woff + carry;
    int total = wsum[15];
    __syncthreads();
    if (tid == 0) carry += total;
    __syncthreads();
  }
}

// also emits inv_e: CSR position of each original edge id
__global__ void scatter_kernel(const int* __restrict__ src, const int* __restrict__ dst,
                               const int* __restrict__ ro, int* __restrict__ cursor,
                               int* __restrict__ s_csr, int* __restrict__ inv_e, int E) {
  int e = blockIdx.x * 256 + threadIdx.x;
  if (e >= E) return;
  int d = dst[e];
  int pos = ro[d] + atomicAdd(&cursor[d], 1);
  s_csr[pos] = src[e];
  inv_e[e] = pos;
}

// =================== edge-bias precompute (both layers, CSR-ordered out) ===================
// eb_w layout: [2][4][16] = 128 floats
__global__ __launch_bounds__(256) void ebias_kernel(const float* __restrict__ ef,
                                                    const float* __restrict__ ebw,
                                                    const int* __restrict__ inv_e,
                                                    float* __restrict__ eb) {
  __shared__ float w[128];
  if (threadIdx.x < 128) w[threadIdx.x] = ebw[threadIdx.x];
  __syncthreads();
  int e = blockIdx.x * 256 + threadIdx.x;
  if (e >= NE) return;
  float f[16];
  #pragma unroll
  for (int i = 0; i < 4; i++) *(float4*)&f[i * 4] = *(const float4*)(ef + (size_t)e * 16 + i * 4);
  int pos = inv_e[e];
  #pragma unroll
  for (int l = 0; l < 2; l++) {
    float4 o;
    float* op = &o.x;
    #pragma unroll
    for (int h = 0; h < 4; h++) {
      float acc = 0.f;
      #pragma unroll
      for (int i = 0; i < 16; i++) acc = fmaf(f[i], w[l * 64 + h * 16 + i], acc);
      op[h] = acc;
    }
    *(float4*)(eb + (size_t)l * NE * 4 + (size_t)pos * 4) = o;
  }
}

// =================== expmap0 ===================
// block = 256 = 4 nodes x 64 lanes; writes split state (hs, ht)
__global__ void expmap_kernel(const float* __restrict__ x, float* __restrict__ hs,
                              float* __restrict__ ht) {
  int nl = threadIdx.x >> 6, lane = threadIdx.x & 63;
  int n = blockIdx.x * 4 + nl;
  if (n >= NN) return;
  const float* xr = x + (size_t)n * 128;
  float v0 = xr[lane], v1 = xr[lane + 64];
  float ss = v0 * v0 + v1 * v1;
  #pragma unroll
  for (int off = 1; off < 64; off <<= 1) ss += __shfl_xor(ss, off);
  float nn = sqrtf(fmaxf(ss, 1e-12f));
  float s = sinhf(nn) / nn;
  float* hr = hs + (size_t)n * 128;
  if (lane == 0) ht[n] = coshf(nn);
  hr[lane] = s * v0;
  hr[lane + 64] = s * v1;
}

// =================== register-resident node GEMM ===================
// block = 64 nodes x 128 cols, 256 threads; thread = 1 node x 32 cols.
// Wave = 64 nodes x one 32-col group -> W address is wave-uniform (scalar loads).
// A rows stream through per-lane float4 loads. No LDS in the K-loop.
// EPI: 0 = LN+ReLU+lift, 1 = per-head lift (qkv), 2 = midpoint2+LN+lift, 3 = logmap0
template<int EPI>
__global__ __launch_bounds__(256, 4) void node_gemm(
    const float* __restrict__ As, const float* __restrict__ At,
    const float* __restrict__ WT, int outc,
    const float* __restrict__ bias,
    float* __restrict__ outS, float* __restrict__ outT, QkvPtrs qo,
    const float* __restrict__ resS, const float* __restrict__ resT,
    const float* __restrict__ gv, const float* __restrict__ bvv) {
  __shared__ float red[2][64][5];
  const int tid = threadIdx.x;
  const int ln = tid & 63;                                    // node within block
  const int grp = __builtin_amdgcn_readfirstlane(tid >> 6);   // col group (wave-uniform)
  const int n = blockIdx.x * 64 + ln;
  const int cb = blockIdx.y;
  const int colOff = (cb << 7) + (grp << 5);

  float acc[32];
  { // k = 0 (time row) folded into init together with bias
    float at = At[n];
    const float* w0 = WT + colOff;
    #pragma unroll
    for (int i = 0; i < 8; i++) {
      float4 b4 = *(const float4*)(bias + colOff + i * 4);
      float4 w4 = *(const float4*)(w0 + i * 4);
      acc[i * 4 + 0] = fmaf(at, w4.x, b4.x);
      acc[i * 4 + 1] = fmaf(at, w4.y, b4.y);
      acc[i * 4 + 2] = fmaf(at, w4.z, b4.z);
      acc[i * 4 + 3] = fmaf(at, w4.w, b4.w);
    }
  }
  const float* Arow = As + (size_t)n * 128;
  for (int k4 = 0; k4 < 32; k4++) {
    float a4[4];
    *(float4*)a4 = *(const float4*)(Arow + (k4 << 2));
    #pragma unroll
    for (int kk = 0; kk < 4; kk++) {
      const float* wp = WT + (size_t)(1 + (k4 << 2) + kk) * outc + colOff;
      float av = a4[kk];
      #pragma unroll
      for (int i = 0; i < 8; i++) {
        float4 w4 = *(const float4*)(wp + i * 4);
        acc[i * 4 + 0] = fmaf(av, w4.x, acc[i * 4 + 0]);
        acc[i * 4 + 1] = fmaf(av, w4.y, acc[i * 4 + 1]);
        acc[i * 4 + 2] = fmaf(av, w4.z, acc[i * 4 + 2]);
        acc[i * 4 + 3] = fmaf(av, w4.w, acc[i * 4 + 3]);
      }
    }
  }

  const int c0 = grp << 5;   // col base within the 128-col output block

  if constexpr (EPI == 0) {           // LayerNorm + ReLU + lift
    float s = 0.f, s2 = 0.f;
    #pragma unroll
    for (int j = 0; j < 32; j++) { s += acc[j]; s2 += acc[j] * acc[j]; }
    red[0][ln][grp] = s; red[1][ln][grp] = s2;
    __syncthreads();
    float S = 0.f, S2 = 0.f;
    #pragma unroll
    for (int q = 0; q < 4; q++) { S += red[0][ln][q]; S2 += red[1][ln][q]; }
    float mu = S * (1.f / 128.f);
    float var = S2 * (1.f / 128.f) - mu * mu;
    float rstd = 1.f / sqrtf(var + 1e-5f);
    float ss = 0.f;
    #pragma unroll
    for (int j = 0; j < 32; j++) {
      float z = (acc[j] - mu) * rstd * gv[c0 + j] + bvv[c0 + j];
      z = fmaxf(z, 0.f);
      ss += z * z;
      acc[j] = z;
    }
    __syncthreads();
    red[0][ln][grp] = ss;
    __syncthreads();
    float SS = red[0][ln][0] + red[0][ln][1] + red[0][ln][2] + red[0][ln][3];
    float* orow = outS + (size_t)n * 128 + c0;
    #pragma unroll
    for (int i = 0; i < 8; i++) *(float4*)(orow + i * 4) = *(float4*)&acc[i * 4];
    if (grp == 0) outT[n] = sqrtf(1.f + SS);
  } else if constexpr (EPI == 1) {    // per-head lift: thread's 32 cols = one head
    float* sp = cb == 0 ? qo.sp0 : (cb == 1 ? qo.sp1 : qo.sp2);
    float* tp = cb == 0 ? qo.tp0 : (cb == 1 ? qo.tp1 : qo.tp2);
    float ss = 0.f;
    #pragma unroll
    for (int j = 0; j < 32; j++) ss += acc[j] * acc[j];
    tp[(size_t)n * 4 + grp] = sqrtf(1.f + ss);
    float* srow = sp + (size_t)n * 128 + c0;
    #pragma unroll
    for (int i = 0; i < 8; i++) *(float4*)(srow + i * 4) = *(float4*)&acc[i * 4];
  } else if constexpr (EPI == 2) {    // lift + midpoint2(res) + LayerNorm + lift
    float sy = 0.f;
    #pragma unroll
    for (int j = 0; j < 32; j++) sy += acc[j] * acc[j];
    red[0][ln][grp] = sy;
    __syncthreads();
    float SY = red[0][ln][0] + red[0][ln][1] + red[0][ln][2] + red[0][ln][3];
    float t_att = sqrtf(1.f + SY);
    float a0 = 0.5f * (t_att + resT[n]);
    const float* rrow = resS + (size_t)n * 128 + c0;
    float sa = 0.f, su = 0.f;
    #pragma unroll
    for (int i = 0; i < 8; i++) {
      float4 r4 = *(const float4*)(rrow + i * 4);
      const float* rp = &r4.x;
      #pragma unroll
      for (int q = 0; q < 4; q++) {
        float a = 0.5f * (acc[i * 4 + q] + rp[q]);
        acc[i * 4 + q] = a;
        sa += a * a;
        su += a;
      }
    }
    __syncthreads();
    red[0][ln][grp] = sa; red[1][ln][grp] = su;
    __syncthreads();
    float SA = 0.f, SU = 0.f;
    #pragma unroll
    for (int q = 0; q < 4; q++) { SA += red[0][ln][q]; SU += red[1][ln][q]; }
    float den = sqrtf(fmaxf(fabsf(a0 * a0 - SA), 1e-8f));
    float inv = 1.f / den;
    float mu = SU * inv * (1.f / 128.f);
    float var = SA * inv * inv * (1.f / 128.f) - mu * mu;
    float rstd = 1.f / sqrtf(var + 1e-5f);
    float ss = 0.f;
    #pragma unroll
    for (int j = 0; j < 32; j++) {
      float z = (acc[j] * inv - mu) * rstd * gv[c0 + j] + bvv[c0 + j];
      ss += z * z;
      acc[j] = z;
    }
    __syncthreads();
    red[0][ln][grp] = ss;
    __syncthreads();
    float SS = red[0][ln][0] + red[0][ln][1] + red[0][ln][2] + red[0][ln][3];
    float* orow = outS + (size_t)n * 128 + c0;
    #pragma unroll
    for (int i = 0; i < 8; i++) *(float4*)(orow + i * 4) = *(float4*)&acc[i * 4];
    if (grp == 0) outT[n] = sqrtf(1.f + SS);
  } else {                            // EPI == 3: lift + logmap0 (packed out)
    float s = 0.f;
    #pragma unroll
    for (int j = 0; j < 32; j++) s += acc[j] * acc[j];
    red[0][ln][grp] = s;
    __syncthreads();
    float S = red[0][ln][0] + red[0][ln][1] + red[0][ln][2] + red[0][ln][3];
    float nn = sqrtf(fmaxf(S, 1e-12f));
    float t0 = sqrtf(1.f + S);
    float al = fmaxf(t0, 1.f + 1e-7f);
    float sc = acoshf(al) / nn;
    float* orow = outS + (size_t)n * 128 + c0;
    #pragma unroll
    for (int j = 0; j < 32; j++) acc[j] *= sc;
    #pragma unroll
    for (int i = 0; i < 8; i++) *(float4*)(orow + i * 4) = *(float4*)&acc[i * 4];
  }
}

// =================== fused edge attention (score + online softmax + aggregate) ===================
// 4 nodes per 256-thread block; one wave per node; lane = (head h = lane/16, d2 = lane%16)
__global__ __launch_bounds__(256) void edge_attn_kernel(const int* __restrict__ ro,
                                                        const int* __restrict__ s_csr,
                                                        const float* __restrict__ ebias,
                                                        const float* __restrict__ qs,
                                                        const float* __restrict__ qt,
                                                        const float* __restrict__ ks,
                                                        const float* __restrict__ kt,
                                                        const float* __restrict__ vs,
                                                        const float* __restrict__ vt,
                                                        float* __restrict__ aggS,
                                                        float* __restrict__ aggT) {
  int n = blockIdx.x * 4 + (threadIdx.x >> 6);
  if (n >= NN) return;
  int lane = threadIdx.x & 63;
  int h = lane >> 4, d2 = lane & 15;
  int r0 = ro[n], deg = ro[n + 1] - r0;

  int qoff = n * 128 + (h << 5) + d2;
  float q0 = qs[qoff], q1 = qs[qoff + 16];
  float qth = qt[(size_t)n * 4 + h];

  float m = -1e30f, den = 0.f, acc0 = 0.f, acc1 = 0.f, acct = 0.f;

  // pipeline regs (next edge)
  int   sN = 0;
  float k0N = 0, k1N = 0, ktN = 0, v0N = 0, v1N = 0, vtN = 0, ebN = 0;
  if (deg > 0) {
    sN = s_csr[r0];
    int so = sN * 128 + (h << 5) + d2;
    k0N = ks[so]; k1N = ks[so + 16];
    v0N = vs[so]; v1N = vs[so + 16];
    ktN = kt[(size_t)sN * 4 + h];
    vtN = vt[(size_t)sN * 4 + h];
    ebN = ebias[(size_t)r0 * 4 + h];
  }
  int s1 = (deg > 1) ? s_csr[r0 + 1] : 0;

  for (int j = 0; j < deg; j++) {
    float k0 = k0N, k1 = k1N, ktc = ktN, v0 = v0N, v1 = v1N, vtc = vtN, eb = ebN;
    if (j + 1 < deg) {
      int so = s1 * 128 + (h << 5) + d2;
      k0N = ks[so]; k1N = ks[so + 16];
      v0N = vs[so]; v1N = vs[so + 16];
      ktN = kt[(size_t)s1 * 4 + h];
      vtN = vt[(size_t)s1 * 4 + h];
      ebN = ebias[(size_t)(r0 + j + 1) * 4 + h];
    }
    if (j + 2 < deg) s1 = s_csr[r0 + j + 2];

    float dp = q0 * k0 + q1 * k1;
    dp += __shfl_xor(dp, 1);
    dp += __shfl_xor(dp, 2);
    dp += __shfl_xor(dp, 4);
    dp += __shfl_xor(dp, 8);
    float sc = (2.f + 2.f * (dp - qth * ktc)) * 0.17677669529663687f + eb;

    float mN = fmaxf(m, sc);
    float scale = expf(m - mN);
    float w = expf(sc - mN);
    den  = den  * scale + w;
    acc0 = acc0 * scale + w * v0;
    acc1 = acc1 * scale + w * v1;
    acct = acct * scale + w * vtc;
    m = mN;
  }

  float inv = 1.f / (den + 1e-16f);
  float a0 = acc0 * inv, a1 = acc1 * inv;
  float at = acct * inv;
  float p = a0 * a0 + a1 * a1;
  p += __shfl_xor(p, 1);
  p += __shfl_xor(p, 2);
  p += __shfl_xor(p, 4);
  p += __shfl_xor(p, 8);
  float dh = sqrtf(fmaxf(fabsf(at * at - p), 1e-8f));
  float o0 = a0 / dh, o1 = a1 / dh;
  float q = o0 * o0 + o1 * o1;
  q += __shfl_xor(q, 1);
  q += __shfl_xor(q, 2);
  q += __shfl_xor(q, 4);
  q += __shfl_xor(q, 8);
  q += __shfl_xor(q, 16);
  q += __shfl_xor(q, 32);
  float* ar = aggS + (size_t)n * 128;
  if (lane == 0) aggT[n] = sqrtf(1.f + q);
  ar[(h << 5) + d2] = o0;
  ar[(h << 5) + 16 + d2] = o1;
}

// =================== launch ===================

extern "C" void kernel_launch(void* const* d_in, const int* in_sizes, int n_in,
                              void* d_out, int out_size, void* d_ws, size_t ws_size,
                              hipStream_t stream) {
  const float* x      = (const float*)d_in[0];
  const int*   ei     = (const int*)  d_in[1];
  const float* ef     = (const float*)d_in[2];
  const float* in_w   = (const float*)d_in[3];
  const float* in_b   = (const float*)d_in[4];
  const float* in_g   = (const float*)d_in[5];
  const float* in_bb  = (const float*)d_in[6];
  const float* q_w    = (const float*)d_in[7];
  const float* q_b    = (const float*)d_in[8];
  const float* k_w    = (const float*)d_in[9];
  const float* k_b    = (const float*)d_in[10];
  const float* v_w    = (const float*)d_in[11];
  const float* v_b    = (const float*)d_in[12];
  const float* out_w  = (const float*)d_in[13];
  const float* out_b  = (const float*)d_in[14];
  const float* eb_w   = (const float*)d_in[15];
  const float* norm_g = (const float*)d_in[16];
  const float* norm_b = (const float*)d_in[17];
  const float* outp_w = (const float*)d_in[18];
  const float* outp_b = (const float*)d_in[19];

  const int* srcI = ei;
  const int* dstI = ei + NE;

  // ---- carve workspace ----
  char* base = (char*)d_ws;
  size_t off = 0;
  auto carve = [&](size_t bytes) -> char* {
    char* p = base + off;
    off = (off + bytes + 255) & ~(size_t)255;
    return p;
  };
  float* hs0    = (float*)carve((size_t)NN * 128 * 4);
  float* ht0    = (float*)carve((size_t)NN * 4);
  float* hs1    = (float*)carve((size_t)NN * 128 * 4);
  float* ht1    = (float*)carve((size_t)NN * 4);
  float* qs     = (float*)carve((size_t)NN * 128 * 4);
  float* qt     = (float*)carve((size_t)NN * 4 * 4);
  float* ks     = (float*)carve((size_t)NN * 128 * 4);
  float* kt     = (float*)carve((size_t)NN * 4 * 4);
  float* vs     = (float*)carve((size_t)NN * 128 * 4);
  float* vt     = (float*)carve((size_t)NN * 4 * 4);
  float* ebias  = (float*)carve((size_t)2 * NE * 4 * 4);
  int*   s_csr  = (int*)  carve((size_t)NE * 4);
  int*   inv_e  = (int*)  carve((size_t)NE * 4);
  int*   ro     = (int*)  carve((size_t)(NN + 1) * 4);
  int*   counts = (int*)  carve((size_t)NN * 4);
  float* WT     = (float*)carve((size_t)WT_TOTAL * 4);
  float* bq     = (float*)carve((size_t)768 * 4);
  if (off > ws_size) return;  // workspace too small; bail

  QkvPtrs qkvp{qs, qt, ks, kt, vs, vt};
  QkvPtrs qz{nullptr, nullptr, nullptr, nullptr, nullptr, nullptr};

  // ---- weight prep ----
  prep_wt<<<(KD * 1280 + 255) / 256, 256, 0, stream>>>(in_w, q_w, k_w, v_w, out_w, outp_w, WT);
  prep_bias<<<3, 256, 0, stream>>>(q_b, k_b, v_b, bq);

  // ---- CSR build (by dst) ----
  zero_i32<<<(NN + 255) / 256, 256, 0, stream>>>(counts, NN);
  count_kernel<<<NE / 256, 256, 0, stream>>>(dstI, counts, NE);
  scan_kernel<<<1, 1024, 0, stream>>>(counts, ro, NN);
  zero_i32<<<(NN + 255) / 256, 256, 0, stream>>>(counts, NN);
  scatter_kernel<<<NE / 256, 256, 0, stream>>>(srcI, dstI, ro, counts, s_csr, inv_e, NE);

  // ---- edge biases for both layers (CSR-ordered) ----
  ebias_kernel<<<(NE + 255) / 256, 256, 0, stream>>>(ef, eb_w, inv_e, ebias);

  // ---- input embedding ----
  expmap_kernel<<<NN / 4, 256, 0, stream>>>(x, hs0, ht0);
  node_gemm<0><<<dim3(NN / 64, 1), 256, 0, stream>>>(hs0, ht0, WT + OFF_IN, 128, in_b,
                                                     hs0, ht0, qz, nullptr, nullptr,
                                                     in_g, in_bb);

  // ---- layers ----
  float* hcS = hs0; float* hcT = ht0;
  float* hoS = hs1; float* hoT = ht1;
  for (int l = 0; l < 2; l++) {
    node_gemm<1><<<dim3(NN / 64, 3), 256, 0, stream>>>(
        hcS, hcT, WT + (l ? OFF_QKV1 : OFF_QKV0), 384, bq + l * 384,
        nullptr, nullptr, qkvp, nullptr, nullptr, nullptr, nullptr);
    edge_attn_kernel<<<NN / 4, 256, 0, stream>>>(ro, s_csr, ebias + (size_t)l * NE * 4,
                                                 qs, qt, ks, kt, vs, vt, hoS, hoT);
    node_gemm<2><<<dim3(NN / 64, 1), 256, 0, stream>>>(
        hoS, hoT, WT + (l ? OFF_OUT1 : OFF_OUT0), 128, out_b + l * 128,
        hoS, hoT, qz, hcS, hcT, norm_g + l * 128, norm_b + l * 128);
    float* t;
    t = hcS; hcS = hoS; hoS = t;
    t = hcT; hcT = hoT; hoT = t;
  }

  // ---- output projection + logmap ----
  node_gemm<3><<<dim3(NN / 64, 1), 256, 0, stream>>>(hcS, hcT, WT + OFF_OUTP, 128, outp_b,
                                                     (float*)d_out, nullptr, qz,
                                                     nullptr, nullptr, nullptr, nullptr);
}

// Round 5
// 667.173 us; speedup vs baseline: 1.3536x; 1.0121x over previous
//
#include <hip/hip_runtime.h>
#include <math.h>

constexpr int NN = 40000;
constexpr int NE = 640000;
constexpr int KD = 129;     // contraction dim (time + 128 space)

constexpr float LOG2E = 1.4426950408889634f;
constexpr float SC_C  = 0.35355339059327373f * LOG2E;   // 2/sqrt(32) * log2(e)

// ---- transposed-weight buffer offsets (in floats) ----
constexpr int OFF_IN   = 0;
constexpr int OFF_QKV0 = OFF_IN   + KD*128;
constexpr int OFF_QKV1 = OFF_QKV0 + KD*384;
constexpr int OFF_OUT0 = OFF_QKV1 + KD*384;
constexpr int OFF_OUT1 = OFF_OUT0 + KD*128;
constexpr int OFF_OUTP = OFF_OUT1 + KD*128;
constexpr int WT_TOTAL = OFF_OUTP + KD*128;   // 165120 floats

struct QkvPtrs {
  float* sp0; float* tp0;
  float* sp1; float* tp1;
  float* sp2; float* tp2;
};

// =================== small utility kernels ===================

__global__ void zero_i32(int* p, int n) {
  int i = blockIdx.x * 256 + threadIdx.x;
  if (i < n) p[i] = 0;
}

// transpose all weights to k-major once per call
__global__ void prep_wt(const float* __restrict__ in_w, const float* __restrict__ q_w,
                        const float* __restrict__ k_w, const float* __restrict__ v_w,
                        const float* __restrict__ out_w, const float* __restrict__ outp_w,
                        float* __restrict__ WT) {
  int t = blockIdx.x * 256 + threadIdx.x;
  if (t >= KD * 1280) return;
  int k = t / 1280, c = t % 1280;
  float v; int dst;
  if (c < 128) {
    v = in_w[(size_t)c * KD + k];
    dst = OFF_IN + k * 128 + c;
  } else if (c < 896) {
    int l = (c - 128) / 384, cc = (c - 128) % 384;
    int arr = cc >> 7, r = cc & 127;
    const float* w = arr == 0 ? q_w : (arr == 1 ? k_w : v_w);
    v = w[((size_t)l * 128 + r) * KD + k];
    dst = (l == 0 ? OFF_QKV0 : OFF_QKV1) + k * 384 + cc;
  } else if (c < 1152) {
    int l = (c - 896) / 128, r = (c - 896) % 128;
    v = out_w[((size_t)l * 128 + r) * KD + k];
    dst = (l == 0 ? OFF_OUT0 : OFF_OUT1) + k * 128 + r;
  } else {
    int r = c - 1152;
    v = outp_w[(size_t)r * KD + k];
    dst = OFF_OUTP + k * 128 + r;
  }
  WT[dst] = v;
}

__global__ void prep_bias(const float* __restrict__ q_b, const float* __restrict__ k_b,
                          const float* __restrict__ v_b, float* __restrict__ bq) {
  int t = blockIdx.x * 256 + threadIdx.x;
  if (t >= 768) return;
  int l = t / 384, c = t % 384;
  int arr = c >> 7, r = c & 127;
  const float* b = arr == 0 ? q_b : (arr == 1 ? k_b : v_b);
  bq[t] = b[l * 128 + r];
}

// =================== CSR build ===================

__global__ void count_kernel(const int* __restrict__ dst, int* __restrict__ counts, int E) {
  int e = blockIdx.x * 256 + threadIdx.x;
  if (e < E) atomicAdd(&counts[dst[e]], 1);
}

__global__ void __launch_bounds__(1024) scan_kernel(const int* __restrict__ counts,
                                                    int* __restrict__ ro, int n) {
  __shared__ int wsum[16];
  __shared__ int carry;
  int tid = threadIdx.x, wid = tid >> 6, lane = tid & 63;
  if (tid == 0) { carry = 0; ro[0] = 0; }
  __syncthreads();
  for (int base = 0; base < n; base += 1024) {
    int idx = base + tid;
    int v = (idx < n) ? counts[idx] : 0;
    int s = v;
    #pragma unroll
    for (int off = 1; off < 64; off <<= 1) {
      int t = __shfl_up(s, off);
      if (lane >= off) s += t;
    }
    if (lane == 63) wsum[wid] = s;
    __syncthreads();
    if (wid == 0) {
      int ws = (lane < 16) ? wsum[lane] : 0;
      #pragma unroll
      for (int off = 1; off < 16; off <<= 1) {
        int t = __shfl_up(ws, off);
        if (lane >= off) ws += t;
      }
      if (lane < 16) wsum[lane] = ws;
    }
    __syncthreads();
    int woff = (wid > 0) ? wsum[wid - 1] : 0;
    if (idx < n) ro[idx + 1] = s + woff + carry;
    int total = wsum[15];
    __syncthreads();
    if (tid == 0) carry += total;
    __syncthreads();
  }
}

// also emits inv_e: CSR position of each original edge id
__global__ void scatter_kernel(const int* __restrict__ src, const int* __restrict__ dst,
                               const int* __restrict__ ro, int* __restrict__ cursor,
                               int* __restrict__ s_csr, int* __restrict__ inv_e, int E) {
  int e = blockIdx.x * 256 + threadIdx.x;
  if (e >= E) return;
  int d = dst[e];
  int pos = ro[d] + atomicAdd(&cursor[d], 1);
  s_csr[pos] = src[e];
  inv_e[e] = pos;
}

// =================== edge-bias precompute (both layers, CSR-ordered out) ===================
// eb_w layout: [2][4][16] = 128 floats. Output is pre-scaled into log2-domain:
//   eb_out = SC_C + (ef @ ebw.T) * LOG2E   (so score = fma(dp_total, SC_C, eb_out))
__global__ __launch_bounds__(256) void ebias_kernel(const float* __restrict__ ef,
                                                    const float* __restrict__ ebw,
                                                    const int* __restrict__ inv_e,
                                                    float* __restrict__ eb) {
  __shared__ float w[128];
  if (threadIdx.x < 128) w[threadIdx.x] = ebw[threadIdx.x];
  __syncthreads();
  int e = blockIdx.x * 256 + threadIdx.x;
  if (e >= NE) return;
  float f[16];
  #pragma unroll
  for (int i = 0; i < 4; i++) *(float4*)&f[i * 4] = *(const float4*)(ef + (size_t)e * 16 + i * 4);
  int pos = inv_e[e];
  #pragma unroll
  for (int l = 0; l < 2; l++) {
    float4 o;
    float* op = &o.x;
    #pragma unroll
    for (int h = 0; h < 4; h++) {
      float acc = 0.f;
      #pragma unroll
      for (int i = 0; i < 16; i++) acc = fmaf(f[i], w[l * 64 + h * 16 + i], acc);
      op[h] = fmaf(acc, LOG2E, SC_C);
    }
    *(float4*)(eb + (size_t)l * NE * 4 + (size_t)pos * 4) = o;
  }
}

// =================== expmap0 ===================
// block = 256 = 4 nodes x 64 lanes; writes split state (hs, ht)
__global__ void expmap_kernel(const float* __restrict__ x, float* __restrict__ hs,
                              float* __restrict__ ht) {
  int nl = threadIdx.x >> 6, lane = threadIdx.x & 63;
  int n = blockIdx.x * 4 + nl;
  if (n >= NN) return;
  const float* xr = x + (size_t)n * 128;
  float v0 = xr[lane], v1 = xr[lane + 64];
  float ss = v0 * v0 + v1 * v1;
  #pragma unroll
  for (int off = 1; off < 64; off <<= 1) ss += __shfl_xor(ss, off);
  float nn = sqrtf(fmaxf(ss, 1e-12f));
  float s = sinhf(nn) / nn;
  float* hr = hs + (size_t)n * 128;
  if (lane == 0) ht[n] = coshf(nn);
  hr[lane] = s * v0;
  hr[lane + 64] = s * v1;
}

// =================== register-resident node GEMM ===================
// block = 64 nodes x 128 cols, 256 threads; thread = 1 node x 32 cols.
// Wave = 64 nodes x one 32-col group -> W address is wave-uniform (scalar loads).
// A rows stream through per-lane float4 loads. No LDS in the K-loop.
// EPI: 0 = LN+ReLU+lift, 1 = per-head lift (qkv), 2 = midpoint2+LN+lift, 3 = logmap0
template<int EPI>
__global__ __launch_bounds__(256, 4) void node_gemm(
    const float* __restrict__ As, const float* __restrict__ At,
    const float* __restrict__ WT, int outc,
    const float* __restrict__ bias,
    float* __restrict__ outS, float* __restrict__ outT, QkvPtrs qo,
    const float* __restrict__ resS, const float* __restrict__ resT,
    const float* __restrict__ gv, const float* __restrict__ bvv) {
  __shared__ float red[2][64][5];
  const int tid = threadIdx.x;
  const int ln = tid & 63;                                    // node within block
  const int grp = __builtin_amdgcn_readfirstlane(tid >> 6);   // col group (wave-uniform)
  const int n = blockIdx.x * 64 + ln;
  const int cb = blockIdx.y;
  const int colOff = (cb << 7) + (grp << 5);

  float acc[32];
  { // k = 0 (time row) folded into init together with bias
    float at = At[n];
    const float* w0 = WT + colOff;
    #pragma unroll
    for (int i = 0; i < 8; i++) {
      float4 b4 = *(const float4*)(bias + colOff + i * 4);
      float4 w4 = *(const float4*)(w0 + i * 4);
      acc[i * 4 + 0] = fmaf(at, w4.x, b4.x);
      acc[i * 4 + 1] = fmaf(at, w4.y, b4.y);
      acc[i * 4 + 2] = fmaf(at, w4.z, b4.z);
      acc[i * 4 + 3] = fmaf(at, w4.w, b4.w);
    }
  }
  const float* Arow = As + (size_t)n * 128;
  for (int k4 = 0; k4 < 32; k4++) {
    float a4[4];
    *(float4*)a4 = *(const float4*)(Arow + (k4 << 2));
    #pragma unroll
    for (int kk = 0; kk < 4; kk++) {
      const float* wp = WT + (size_t)(1 + (k4 << 2) + kk) * outc + colOff;
      float av = a4[kk];
      #pragma unroll
      for (int i = 0; i < 8; i++) {
        float4 w4 = *(const float4*)(wp + i * 4);
        acc[i * 4 + 0] = fmaf(av, w4.x, acc[i * 4 + 0]);
        acc[i * 4 + 1] = fmaf(av, w4.y, acc[i * 4 + 1]);
        acc[i * 4 + 2] = fmaf(av, w4.z, acc[i * 4 + 2]);
        acc[i * 4 + 3] = fmaf(av, w4.w, acc[i * 4 + 3]);
      }
    }
  }

  const int c0 = grp << 5;   // col base within the 128-col output block

  if constexpr (EPI == 0) {           // LayerNorm + ReLU + lift
    float s = 0.f, s2 = 0.f;
    #pragma unroll
    for (int j = 0; j < 32; j++) { s += acc[j]; s2 += acc[j] * acc[j]; }
    red[0][ln][grp] = s; red[1][ln][grp] = s2;
    __syncthreads();
    float S = 0.f, S2 = 0.f;
    #pragma unroll
    for (int q = 0; q < 4; q++) { S += red[0][ln][q]; S2 += red[1][ln][q]; }
    float mu = S * (1.f / 128.f);
    float var = S2 * (1.f / 128.f) - mu * mu;
    float rstd = 1.f / sqrtf(var + 1e-5f);
    float ss = 0.f;
    #pragma unroll
    for (int j = 0; j < 32; j++) {
      float z = (acc[j] - mu) * rstd * gv[c0 + j] + bvv[c0 + j];
      z = fmaxf(z, 0.f);
      ss += z * z;
      acc[j] = z;
    }
    __syncthreads();
    red[0][ln][grp] = ss;
    __syncthreads();
    float SS = red[0][ln][0] + red[0][ln][1] + red[0][ln][2] + red[0][ln][3];
    float* orow = outS + (size_t)n * 128 + c0;
    #pragma unroll
    for (int i = 0; i < 8; i++) *(float4*)(orow + i * 4) = *(float4*)&acc[i * 4];
    if (grp == 0) outT[n] = sqrtf(1.f + SS);
  } else if constexpr (EPI == 1) {    // per-head lift: thread's 32 cols = one head
    float* sp = cb == 0 ? qo.sp0 : (cb == 1 ? qo.sp1 : qo.sp2);
    float* tp = cb == 0 ? qo.tp0 : (cb == 1 ? qo.tp1 : qo.tp2);
    const int tst = (cb == 0) ? 1 : 2;   // k/v time coords interleave into ktv float2
    float ss = 0.f;
    #pragma unroll
    for (int j = 0; j < 32; j++) ss += acc[j] * acc[j];
    tp[((size_t)n * 4 + grp) * tst] = sqrtf(1.f + ss);
    float* srow = sp + (size_t)n * 128 + c0;
    #pragma unroll
    for (int i = 0; i < 8; i++) *(float4*)(srow + i * 4) = *(float4*)&acc[i * 4];
  } else if constexpr (EPI == 2) {    // lift + midpoint2(res) + LayerNorm + lift
    float sy = 0.f;
    #pragma unroll
    for (int j = 0; j < 32; j++) sy += acc[j] * acc[j];
    red[0][ln][grp] = sy;
    __syncthreads();
    float SY = red[0][ln][0] + red[0][ln][1] + red[0][ln][2] + red[0][ln][3];
    float t_att = sqrtf(1.f + SY);
    float a0 = 0.5f * (t_att + resT[n]);
    const float* rrow = resS + (size_t)n * 128 + c0;
    float sa = 0.f, su = 0.f;
    #pragma unroll
    for (int i = 0; i < 8; i++) {
      float4 r4 = *(const float4*)(rrow + i * 4);
      const float* rp = &r4.x;
      #pragma unroll
      for (int q = 0; q < 4; q++) {
        float a = 0.5f * (acc[i * 4 + q] + rp[q]);
        acc[i * 4 + q] = a;
        sa += a * a;
        su += a;
      }
    }
    __syncthreads();
    red[0][ln][grp] = sa; red[1][ln][grp] = su;
    __syncthreads();
    float SA = 0.f, SU = 0.f;
    #pragma unroll
    for (int q = 0; q < 4; q++) { SA += red[0][ln][q]; SU += red[1][ln][q]; }
    float den = sqrtf(fmaxf(fabsf(a0 * a0 - SA), 1e-8f));
    float inv = 1.f / den;
    float mu = SU * inv * (1.f / 128.f);
    float var = SA * inv * inv * (1.f / 128.f) - mu * mu;
    float rstd = 1.f / sqrtf(var + 1e-5f);
    float ss = 0.f;
    #pragma unroll
    for (int j = 0; j < 32; j++) {
      float z = (acc[j] * inv - mu) * rstd * gv[c0 + j] + bvv[c0 + j];
      ss += z * z;
      acc[j] = z;
    }
    __syncthreads();
    red[0][ln][grp] = ss;
    __syncthreads();
    float SS = red[0][ln][0] + red[0][ln][1] + red[0][ln][2] + red[0][ln][3];
    float* orow = outS + (size_t)n * 128 + c0;
    #pragma unroll
    for (int i = 0; i < 8; i++) *(float4*)(orow + i * 4) = *(float4*)&acc[i * 4];
    if (grp == 0) outT[n] = sqrtf(1.f + SS);
  } else {                            // EPI == 3: lift + logmap0 (packed out)
    float s = 0.f;
    #pragma unroll
    for (int j = 0; j < 32; j++) s += acc[j] * acc[j];
    red[0][ln][grp] = s;
    __syncthreads();
    float S = red[0][ln][0] + red[0][ln][1] + red[0][ln][2] + red[0][ln][3];
    float nn = sqrtf(fmaxf(S, 1e-12f));
    float t0 = sqrtf(1.f + S);
    float al = fmaxf(t0, 1.f + 1e-7f);
    float sc = acoshf(al) / nn;
    float* orow = outS + (size_t)n * 128 + c0;
    #pragma unroll
    for (int j = 0; j < 32; j++) acc[j] *= sc;
    #pragma unroll
    for (int i = 0; i < 8; i++) *(float4*)(orow + i * 4) = *(float4*)&acc[i * 4];
  }
}

// =================== fused edge attention (score + online softmax + aggregate) ===================
// 4 nodes per 256-thread block; one wave per node; lane = (head h = lane/16, d2 = lane%16)
// Softmax is computed in the exp2 domain (scores pre-scaled by log2e).
__global__ __launch_bounds__(256) void edge_attn_kernel(const int* __restrict__ ro,
                                                        const int* __restrict__ s_csr,
                                                        const float* __restrict__ ebias,
                                                        const float* __restrict__ qs,
                                                        const float* __restrict__ qt,
                                                        const float* __restrict__ ks,
                                                        const float2* __restrict__ ktv,
                                                        const float* __restrict__ vs,
                                                        float* __restrict__ aggS,
                                                        float* __restrict__ aggT) {
  int n = blockIdx.x * 4 + (threadIdx.x >> 6);
  if (n >= NN) return;
  int lane = threadIdx.x & 63;
  int h = lane >> 4, d2 = lane & 15;
  int r0 = ro[n], deg = ro[n + 1] - r0;

  int qoff = n * 128 + (h << 5) + d2;
  float q0 = qs[qoff], q1 = qs[qoff + 16];
  float qth = qt[(size_t)n * 4 + h];

  float m = -1e30f, den = 0.f, acc0 = 0.f, acc1 = 0.f, acct = 0.f;

  // pipeline regs (next edge)
  float k0N = 0, k1N = 0, v0N = 0, v1N = 0, ebN = 0;
  float2 tvN = {0.f, 0.f};
  if (deg > 0) {
    int sN = s_csr[r0];
    int so = sN * 128 + (h << 5) + d2;
    k0N = ks[so]; k1N = ks[so + 16];
    v0N = vs[so]; v1N = vs[so + 16];
    tvN = ktv[(size_t)sN * 4 + h];
    ebN = ebias[(size_t)r0 * 4 + h];
  }
  int s1 = (deg > 1) ? s_csr[r0 + 1] : 0;

  for (int j = 0; j < deg; j++) {
    float k0 = k0N, k1 = k1N, v0 = v0N, v1 = v1N, eb = ebN;
    float2 tv = tvN;
    if (j + 1 < deg) {
      int so = s1 * 128 + (h << 5) + d2;
      k0N = ks[so]; k1N = ks[so + 16];
      v0N = vs[so]; v1N = vs[so + 16];
      tvN = ktv[(size_t)s1 * 4 + h];
      ebN = ebias[(size_t)(r0 + j + 1) * 4 + h];
    }
    if (j + 2 < deg) s1 = s_csr[r0 + j + 2];

    float dp = q0 * k0 + q1 * k1;
    dp += __shfl_xor(dp, 1);
    dp += __shfl_xor(dp, 2);
    dp += __shfl_xor(dp, 4);
    dp += __shfl_xor(dp, 8);
    float dpt = dp - qth * tv.x;
    float sc = fmaf(dpt, SC_C, eb);      // log2-domain score

    float mN = fmaxf(m, sc);
    float scale = __builtin_amdgcn_exp2f(m - mN);
    float w = __builtin_amdgcn_exp2f(sc - mN);
    den  = den  * scale + w;
    acc0 = acc0 * scale + w * v0;
    acc1 = acc1 * scale + w * v1;
    acct = acct * scale + w * tv.y;
    m = mN;
  }

  float inv = 1.f / (den + 1e-16f);
  float a0 = acc0 * inv, a1 = acc1 * inv;
  float at = acct * inv;
  float p = a0 * a0 + a1 * a1;
  p += __shfl_xor(p, 1);
  p += __shfl_xor(p, 2);
  p += __shfl_xor(p, 4);
  p += __shfl_xor(p, 8);
  float dh = sqrtf(fmaxf(fabsf(at * at - p), 1e-8f));
  float o0 = a0 / dh, o1 = a1 / dh;
  float q = o0 * o0 + o1 * o1;
  q += __shfl_xor(q, 1);
  q += __shfl_xor(q, 2);
  q += __shfl_xor(q, 4);
  q += __shfl_xor(q, 8);
  q += __shfl_xor(q, 16);
  q += __shfl_xor(q, 32);
  float* ar = aggS + (size_t)n * 128;
  if (lane == 0) aggT[n] = sqrtf(1.f + q);
  ar[(h << 5) + d2] = o0;
  ar[(h << 5) + 16 + d2] = o1;
}

// =================== launch ===================

extern "C" void kernel_launch(void* const* d_in, const int* in_sizes, int n_in,
                              void* d_out, int out_size, void* d_ws, size_t ws_size,
                              hipStream_t stream) {
  const float* x      = (const float*)d_in[0];
  const int*   ei     = (const int*)  d_in[1];
  const float* ef     = (const float*)d_in[2];
  const float* in_w   = (const float*)d_in[3];
  const float* in_b   = (const float*)d_in[4];
  const float* in_g   = (const float*)d_in[5];
  const float* in_bb  = (const float*)d_in[6];
  const float* q_w    = (const float*)d_in[7];
  const float* q_b    = (const float*)d_in[8];
  const float* k_w    = (const float*)d_in[9];
  const float* k_b    = (const float*)d_in[10];
  const float* v_w    = (const float*)d_in[11];
  const float* v_b    = (const float*)d_in[12];
  const float* out_w  = (const float*)d_in[13];
  const float* out_b  = (const float*)d_in[14];
  const float* eb_w   = (const float*)d_in[15];
  const float* norm_g = (const float*)d_in[16];
  const float* norm_b = (const float*)d_in[17];
  const float* outp_w = (const float*)d_in[18];
  const float* outp_b = (const float*)d_in[19];

  const int* srcI = ei;
  const int* dstI = ei + NE;

  // ---- carve workspace ----
  char* base = (char*)d_ws;
  size_t off = 0;
  auto carve = [&](size_t bytes) -> char* {
    char* p = base + off;
    off = (off + bytes + 255) & ~(size_t)255;
    return p;
  };
  float* hs0    = (float*)carve((size_t)NN * 128 * 4);
  float* ht0    = (float*)carve((size_t)NN * 4);
  float* hs1    = (float*)carve((size_t)NN * 128 * 4);
  float* ht1    = (float*)carve((size_t)NN * 4);
  float* qs     = (float*)carve((size_t)NN * 128 * 4);
  float* qt     = (float*)carve((size_t)NN * 4 * 4);
  float* ks     = (float*)carve((size_t)NN * 128 * 4);
  float* vs     = (float*)carve((size_t)NN * 128 * 4);
  float2* ktv   = (float2*)carve((size_t)NN * 4 * 8);
  float* ebias  = (float*)carve((size_t)2 * NE * 4 * 4);
  int*   s_csr  = (int*)  carve((size_t)NE * 4);
  int*   inv_e  = (int*)  carve((size_t)NE * 4);
  int*   ro     = (int*)  carve((size_t)(NN + 1) * 4);
  int*   counts = (int*)  carve((size_t)NN * 4);
  float* WT     = (float*)carve((size_t)WT_TOTAL * 4);
  float* bq     = (float*)carve((size_t)768 * 4);
  if (off > ws_size) return;  // workspace too small; bail

  QkvPtrs qkvp{qs, qt, ks, (float*)ktv, vs, (float*)ktv + 1};
  QkvPtrs qz{nullptr, nullptr, nullptr, nullptr, nullptr, nullptr};

  // ---- weight prep ----
  prep_wt<<<(KD * 1280 + 255) / 256, 256, 0, stream>>>(in_w, q_w, k_w, v_w, out_w, outp_w, WT);
  prep_bias<<<3, 256, 0, stream>>>(q_b, k_b, v_b, bq);

  // ---- CSR build (by dst) ----
  zero_i32<<<(NN + 255) / 256, 256, 0, stream>>>(counts, NN);
  count_kernel<<<NE / 256, 256, 0, stream>>>(dstI, counts, NE);
  scan_kernel<<<1, 1024, 0, stream>>>(counts, ro, NN);
  zero_i32<<<(NN + 255) / 256, 256, 0, stream>>>(counts, NN);
  scatter_kernel<<<NE / 256, 256, 0, stream>>>(srcI, dstI, ro, counts, s_csr, inv_e, NE);

  // ---- edge biases for both layers (CSR-ordered, log2-domain) ----
  ebias_kernel<<<(NE + 255) / 256, 256, 0, stream>>>(ef, eb_w, inv_e, ebias);

  // ---- input embedding ----
  expmap_kernel<<<NN / 4, 256, 0, stream>>>(x, hs0, ht0);
  node_gemm<0><<<dim3(NN / 64, 1), 256, 0, stream>>>(hs0, ht0, WT + OFF_IN, 128, in_b,
                                                     hs0, ht0, qz, nullptr, nullptr,
                                                     in_g, in_bb);

  // ---- layers ----
  float* hcS = hs0; float* hcT = ht0;
  float* hoS = hs1; float* hoT = ht1;
  for (int l = 0; l < 2; l++) {
    node_gemm<1><<<dim3(NN / 64, 3), 256, 0, stream>>>(
        hcS, hcT, WT + (l ? OFF_QKV1 : OFF_QKV0), 384, bq + l * 384,
        nullptr, nullptr, qkvp, nullptr, nullptr, nullptr, nullptr);
    edge_attn_kernel<<<NN / 4, 256, 0, stream>>>(ro, s_csr, ebias + (size_t)l * NE * 4,
                                                 qs, qt, ks, ktv, vs, hoS, hoT);
    node_gemm<2><<<dim3(NN / 64, 1), 256, 0, stream>>>(
        hoS, hoT, WT + (l ? OFF_OUT1 : OFF_OUT0), 128, out_b + l * 128,
        hoS, hoT, qz, hcS, hcT, norm_g + l * 128, norm_b + l * 128);
    float* t;
    t = hcS; hcS = hoS; hoS = t;
    t = hcT; hcT = hoT; hoT = t;
  }

  // ---- output projection + logmap ----
  node_gemm<3><<<dim3(NN / 64, 1), 256, 0, stream>>>(hcS, hcT, WT + OFF_OUTP, 128, outp_b,
                                                     (float*)d_out, nullptr, qz,
                                                     nullptr, nullptr, nullptr, nullptr);
}